// Round 4
// baseline (312.488 us; speedup 1.0000x reference)
//
#include <hip/hip_runtime.h>
#include <hip/hip_bf16.h>

#define NROWS 8192
#define DIM 256
#define NT 64                     // 128-row tiles per matrix dim
#define TRI ((NT * (NT + 1)) / 2) // 2080 triangular tiles
#define NBLK (2 * TRI + NT * NT)  // 8256 total blocks

typedef __attribute__((ext_vector_type(8))) short short8;
typedef __attribute__((ext_vector_type(4))) float f32x4;

__device__ __forceinline__ ushort f2bf(float f) {
  unsigned u = __float_as_uint(f);
  u += 0x7fffu + ((u >> 16) & 1u);   // round-to-nearest-even
  return (ushort)(u >> 16);
}
__device__ __forceinline__ float bf2f(ushort b) {
  return __uint_as_float(((unsigned)b) << 16);
}

// scale folded into x2: exp(-0.5*d2) = exp2(C*d2), C = -0.5*log2(e)
#define NEGHALF_LOG2E (-0.72134752044448170368f)
#define LOG2E          (1.44269504088896340736f)

// ---- prep: f32 -> bf16 + row sum-of-squares (of the bf16-rounded values),
// pre-scaled by C. Also zeroes the accumulator + completion counter.
__global__ __launch_bounds__(256) void prep_kernel(
    const float* __restrict__ S, const float* __restrict__ T,
    ushort* __restrict__ Sb, ushort* __restrict__ Tb,
    float* __restrict__ x2s, float* __restrict__ x2t,
    float* __restrict__ accums) {
  if (blockIdx.x == 0 && threadIdx.x == 0) {
    accums[0] = 0.f;                       // kernel-sum accumulator
    ((unsigned*)accums)[1] = 0u;           // block completion counter
  }
  const int w = threadIdx.x >> 6, l = threadIdx.x & 63;
  const int r = blockIdx.x * 4 + w;
  const float* src;
  ushort* dst;
  float* sq;
  int row;
  if (r < NROWS) { src = S; dst = Sb; sq = x2s; row = r; }
  else           { src = T; dst = Tb; sq = x2t; row = r - NROWS; }

  const float4 v = *(const float4*)(src + (size_t)row * DIM + l * 4);
  float vf[4] = {v.x, v.y, v.z, v.w};
  ushort b[4];
  float s = 0.f;
#pragma unroll
  for (int i = 0; i < 4; ++i) {
    b[i] = f2bf(vf[i]);
    float f = bf2f(b[i]);
    s += f * f;
  }
  *(ushort4*)(dst + (size_t)row * DIM + l * 4) = make_ushort4(b[0], b[1], b[2], b[3]);
#pragma unroll
  for (int off = 32; off > 0; off >>= 1) s += __shfl_xor(s, off);
  if (l == 0) sq[row] = s * NEGHALF_LOG2E;
}

__device__ __forceinline__ void gload_lds16(const void* g, void* lds) {
  __builtin_amdgcn_global_load_lds(
      (const __attribute__((address_space(1))) unsigned int*)g,
      (__attribute__((address_space(3))) unsigned int*)lds, 16, 0, 0);
}

// ---- fused GEMM + exp2 + reduce. 128x128 tile, BK=64, swizzled LDS slots.
// Grid: TRI (SS, tr>=tc) + TRI (TT) + NT*NT (ST) = 8256 blocks.
__global__ __launch_bounds__(256) void mmd_gemm(
    const ushort* __restrict__ Sb, const ushort* __restrict__ Tb,
    const float* __restrict__ x2s, const float* __restrict__ x2t,
    float* __restrict__ accums, float* __restrict__ out) {
  __shared__ __align__(16) ushort lA[128 * 64];   // [row][64] bf16, slots swizzled
  __shared__ __align__(16) ushort lB[128 * 64];
  __shared__ float lAx2[128];
  __shared__ float lBx2[128];
  __shared__ float wsum[4];

  const int tid = threadIdx.x;
  const int l = tid & 63;
  const int w = tid >> 6;
  const int wr = w >> 1, wc = w & 1;   // 2x2 waves over the 128x128 tile

  // ---- tile decode: [0,TRI) SS lower-tri, [TRI,2TRI) TT lower-tri, rest ST full
  const int bid = blockIdx.x;
  const ushort* Ap;
  const ushort* Bp;
  const float* a2;
  const float* b2;
  int tr, tc;
  float wgt;
  if (bid < 2 * TRI) {
    const int i = (bid < TRI) ? bid : bid - TRI;
    int g = (int)((sqrtf((float)(8 * i + 1)) - 1.0f) * 0.5f);
    g = min(max(g - 2, 0), NT - 1);
    tr = g;
    while (tr < NT - 1 && (tr + 1) * (tr + 2) / 2 <= i) ++tr;   // <= 3 steps
    tc = i - tr * (tr + 1) / 2;        // tr >= tc
    wgt = (tr == tc) ? 1.f : 2.f;
    if (bid < TRI) { Ap = Sb; Bp = Sb; a2 = x2s; b2 = x2s; }
    else           { Ap = Tb; Bp = Tb; a2 = x2t; b2 = x2t; }
  } else {
    const int t = bid - 2 * TRI;
    tr = t >> 6; tc = t & 63;
    wgt = -2.f;
    Ap = Sb; Bp = Tb; a2 = x2s; b2 = x2t;
  }

  const int aRow0 = tr * 128, bRow0 = tc * 128;

  if (tid < 128) lAx2[tid] = a2[aRow0 + tid];
  else           lBx2[tid - 128] = b2[bRow0 + tid - 128];

  f32x4 acc[4][4];
  const f32x4 zero = {0.f, 0.f, 0.f, 0.f};
#pragma unroll
  for (int m = 0; m < 4; ++m)
#pragma unroll
    for (int n = 0; n < 4; ++n) acc[m][n] = zero;

#pragma unroll
  for (int ks = 0; ks < 4; ++ks) {
    const int k0 = ks * 64;
    // stage: 128 rows x 8 slots of 16B per tile; LDS dest linear, global
    // source pre-swizzled (slot ^= row&7) so swizzled reads see logical data
#pragma unroll
    for (int i = 0; i < 4; ++i) {
      const int c = i * 256 + tid;        // chunk 0..1023
      const int r = c >> 3, t = c & 7;
      const int kg = k0 + ((t ^ (r & 7)) << 3);
      gload_lds16(Ap + (size_t)(aRow0 + r) * DIM + kg, &lA[c * 8]);
      gload_lds16(Bp + (size_t)(bRow0 + r) * DIM + kg, &lB[c * 8]);
    }
    __syncthreads();

#pragma unroll
    for (int kk = 0; kk < 2; ++kk) {
      short8 af[4], bfv[4];
#pragma unroll
      for (int m = 0; m < 4; ++m) {
        const int row = wr * 64 + m * 16 + (l & 15);
        const int slot = (kk * 4 + (l >> 4)) ^ (row & 7);
        af[m] = *(const short8*)&lA[row * 64 + slot * 8];
      }
#pragma unroll
      for (int n = 0; n < 4; ++n) {
        const int row = wc * 64 + n * 16 + (l & 15);
        const int slot = (kk * 4 + (l >> 4)) ^ (row & 7);
        bfv[n] = *(const short8*)&lB[row * 64 + slot * 8];
      }
#pragma unroll
      for (int m = 0; m < 4; ++m)
#pragma unroll
        for (int n = 0; n < 4; ++n)
          acc[m][n] = __builtin_amdgcn_mfma_f32_16x16x32_bf16(af[m], bfv[n], acc[m][n], 0, 0, 0);
    }
    __syncthreads();
  }

  // ---- fused epilogue: arg = C*(x2_i + x2_j) + log2e*dot, clamp <=0, exp2
  float cb[4];
#pragma unroll
  for (int n = 0; n < 4; ++n) cb[n] = lBx2[wc * 64 + n * 16 + (l & 15)];
  float local = 0.f;
#pragma unroll
  for (int m = 0; m < 4; ++m) {
#pragma unroll
    for (int j = 0; j < 4; ++j) {
      const float rc = lAx2[wr * 64 + m * 16 + ((l >> 4) * 4 + j)];
#pragma unroll
      for (int n = 0; n < 4; ++n) {
        float arg = fmaf(LOG2E, acc[m][n][j], rc + cb[n]);
        arg = fminf(arg, 0.f);
        local += exp2f(arg);
      }
    }
  }
#pragma unroll
  for (int off = 32; off > 0; off >>= 1) local += __shfl_xor(local, off);
  if (l == 0) wsum[w] = local;
  __syncthreads();

  if (tid == 0) {
    const float tot = (wsum[0] + wsum[1] + wsum[2] + wsum[3]) * wgt;
    atomicAdd(&accums[0], tot);
    __threadfence();
    const unsigned old = atomicAdd(&((unsigned*)accums)[1], 1u);
    if (old == (unsigned)(NBLK - 1)) {
      __threadfence();
      const float a = atomicAdd(&accums[0], 0.0f);   // coherent read
      out[0] = a * (1.f / ((float)NROWS * (float)NROWS));
    }
  }
}

extern "C" void kernel_launch(void* const* d_in, const int* in_sizes, int n_in,
                              void* d_out, int out_size, void* d_ws, size_t ws_size,
                              hipStream_t stream) {
  const float* S = (const float*)d_in[0];
  const float* T = (const float*)d_in[1];
  float* out = (float*)d_out;

  ushort* Sb = (ushort*)d_ws;                      // 4 MB
  ushort* Tb = Sb + (size_t)NROWS * DIM;           // 4 MB
  float* x2s = (float*)(Tb + (size_t)NROWS * DIM); // 32 KB
  float* x2t = x2s + NROWS;                        // 32 KB
  float* accums = x2t + NROWS;                     // [0]=sum, [1]=counter

  prep_kernel<<<(2 * NROWS) / 4, 256, 0, stream>>>(S, T, Sb, Tb, x2s, x2t, accums);
  mmd_gemm<<<NBLK, 256, 0, stream>>>(Sb, Tb, x2s, x2t, accums, out);
}

// Round 5
// 184.198 us; speedup vs baseline: 1.6965x; 1.6965x over previous
//
#include <hip/hip_runtime.h>
#include <hip/hip_bf16.h>

#define NROWS 8192
#define DIM 256
#define NT 32                     // 256-row tiles per matrix dim
#define TRI ((NT * (NT + 1)) / 2) // 528 triangular tiles
#define NBLK (2 * TRI + NT * NT)  // 2080 total blocks

typedef __attribute__((ext_vector_type(8))) short short8;
typedef __attribute__((ext_vector_type(4))) float f32x4;

__device__ __forceinline__ ushort f2bf(float f) {
  unsigned u = __float_as_uint(f);
  u += 0x7fffu + ((u >> 16) & 1u);   // round-to-nearest-even
  return (ushort)(u >> 16);
}
__device__ __forceinline__ float bf2f(ushort b) {
  return __uint_as_float(((unsigned)b) << 16);
}

// exp(-0.5*d2) = exp2(C*d2), C = -0.5*log2(e); C folded into x2 at prep
#define NEGHALF_LOG2E (-0.72134752044448170368f)
#define LOG2E          (1.44269504088896340736f)

// ---- prep: f32 -> bf16 + row sum-of-squares of the bf16-rounded values.
__global__ __launch_bounds__(256) void prep_kernel(
    const float* __restrict__ S, const float* __restrict__ T,
    ushort* __restrict__ Sb, ushort* __restrict__ Tb,
    float* __restrict__ x2s, float* __restrict__ x2t,
    float* __restrict__ accums) {
  if (blockIdx.x == 0 && threadIdx.x == 0) accums[0] = 0.f;
  const int w = threadIdx.x >> 6, l = threadIdx.x & 63;
  const int r = blockIdx.x * 4 + w;
  const float* src;
  ushort* dst;
  float* sq;
  int row;
  if (r < NROWS) { src = S; dst = Sb; sq = x2s; row = r; }
  else           { src = T; dst = Tb; sq = x2t; row = r - NROWS; }

  const float4 v = *(const float4*)(src + (size_t)row * DIM + l * 4);
  float vf[4] = {v.x, v.y, v.z, v.w};
  ushort b[4];
  float s = 0.f;
#pragma unroll
  for (int i = 0; i < 4; ++i) {
    b[i] = f2bf(vf[i]);
    float f = bf2f(b[i]);
    s += f * f;
  }
  *(ushort4*)(dst + (size_t)row * DIM + l * 4) = make_ushort4(b[0], b[1], b[2], b[3]);
#pragma unroll
  for (int off = 32; off > 0; off >>= 1) s += __shfl_xor(s, off);
  if (l == 0) sq[row] = s * NEGHALF_LOG2E;
}

__device__ __forceinline__ void gload_lds16(const void* g, void* lds) {
  __builtin_amdgcn_global_load_lds(
      (const __attribute__((address_space(1))) unsigned int*)g,
      (__attribute__((address_space(3))) unsigned int*)lds, 16, 0, 0);
}

// ---- fused GEMM + exp2 + reduce. 256x256 tile, 8 waves, BK=32,
// double-buffered LDS with counted vmcnt (T3/T4 minimum 2-phase).
__global__ __launch_bounds__(512, 2) void mmd_gemm(
    const ushort* __restrict__ Sb, const ushort* __restrict__ Tb,
    const float* __restrict__ x2s, const float* __restrict__ x2t,
    float* __restrict__ accums) {
  __shared__ __align__(16) ushort lA[2][256 * 32];  // [buf][row*32 + k], linear
  __shared__ __align__(16) ushort lB[2][256 * 32];
  __shared__ float lAx2[256];
  __shared__ float lBx2[256];
  __shared__ float wsum[8];

  const int tid = threadIdx.x;
  const int l = tid & 63;
  const int w = tid >> 6;
  const int wr = w >> 2, wc = w & 3;   // 2(M) x 4(N) waves; wave tile 128x64

  // ---- tile decode: [0,TRI) SS lower-tri, [TRI,2TRI) TT lower-tri, rest ST
  const int bid = blockIdx.x;
  const ushort* Ap;
  const ushort* Bp;
  const float* a2;
  const float* b2;
  int tr, tc;
  float wgt;
  if (bid < 2 * TRI) {
    const int i = (bid < TRI) ? bid : bid - TRI;
    int g = (int)((sqrtf((float)(8 * i + 1)) - 1.0f) * 0.5f);
    g = min(max(g - 2, 0), NT - 1);
    tr = g;
    while (tr < NT - 1 && (tr + 1) * (tr + 2) / 2 <= i) ++tr;
    tc = i - tr * (tr + 1) / 2;        // tr >= tc
    wgt = (tr == tc) ? 1.f : 2.f;
    if (bid < TRI) { Ap = Sb; Bp = Sb; a2 = x2s; b2 = x2s; }
    else           { Ap = Tb; Bp = Tb; a2 = x2t; b2 = x2t; }
  } else {
    const int t = bid - 2 * TRI;
    tr = t >> 5; tc = t & 31;
    wgt = -2.f;
    Ap = Sb; Bp = Tb; a2 = x2s; b2 = x2t;
  }

  const ushort* gA = Ap + (size_t)(tr * 256) * DIM;  // A tile base (256 rows)
  const ushort* gB = Bp + (size_t)(tc * 256) * DIM;

  // x2 rows into LDS (consumed in epilogue; barriers in loop order it)
  if (tid < 256) lAx2[tid] = a2[tr * 256 + tid];
  else           lBx2[tid - 256] = b2[tc * 256 + tid - 256];

  f32x4 acc[8][4];
  const f32x4 zero = {0.f, 0.f, 0.f, 0.f};
#pragma unroll
  for (int m = 0; m < 8; ++m)
#pragma unroll
    for (int n = 0; n < 4; ++n) acc[m][n] = zero;

  // ---- staging: 1024 16B-chunks per tile, 2 per thread, round-1 pattern
  // (per instruction: 16 consecutive rows/wave, 4 lanes x 64B contiguous)
#define STAGE(buf, k0)                                                     \
  {                                                                        \
    _Pragma("unroll")                                                      \
    for (int j = 0; j < 2; ++j) {                                          \
      const int c = j * 512 + tid;                                         \
      const int row_ = c >> 2, kc_ = c & 3;                                \
      gload_lds16(gA + (size_t)row_ * DIM + (k0) + kc_ * 8, &lA[buf][c * 8]); \
      gload_lds16(gB + (size_t)row_ * DIM + (k0) + kc_ * 8, &lB[buf][c * 8]); \
    }                                                                      \
  }

#define COMPUTE(buf)                                                       \
  {                                                                        \
    short8 af[8], bfv[4];                                                  \
    _Pragma("unroll")                                                      \
    for (int m = 0; m < 8; ++m) {                                          \
      const int row_ = wr * 128 + m * 16 + (l & 15);                       \
      af[m] = *(const short8*)&lA[buf][row_ * 32 + (l >> 4) * 8];          \
    }                                                                      \
    _Pragma("unroll")                                                      \
    for (int n = 0; n < 4; ++n) {                                          \
      const int row_ = wc * 64 + n * 16 + (l & 15);                        \
      bfv[n] = *(const short8*)&lB[buf][row_ * 32 + (l >> 4) * 8];         \
    }                                                                      \
    __builtin_amdgcn_s_setprio(1);                                         \
    _Pragma("unroll")                                                      \
    for (int m = 0; m < 8; ++m)                                            \
      _Pragma("unroll")                                                    \
      for (int n = 0; n < 4; ++n)                                          \
        acc[m][n] = __builtin_amdgcn_mfma_f32_16x16x32_bf16(               \
            af[m], bfv[n], acc[m][n], 0, 0, 0);                            \
    __builtin_amdgcn_s_setprio(0);                                         \
  }

  STAGE(0, 0);                         // prologue: tile 0 in flight
#pragma unroll
  for (int ks = 0; ks < 8; ++ks) {
    const int cur = ks & 1;
    if (ks < 7) {
      STAGE(cur ^ 1, (ks + 1) * 32);   // issue next tile's loads (4 VMEM)
      asm volatile("s_waitcnt vmcnt(4)" ::: "memory");  // my current-tile loads done
    } else {
      asm volatile("s_waitcnt vmcnt(0)" ::: "memory");
    }
    __builtin_amdgcn_s_barrier();      // all waves' current tile visible
    asm volatile("" ::: "memory");
    COMPUTE(cur);                      // ds_reads consumed by MFMA => retired
    asm volatile("" ::: "memory");
    __builtin_amdgcn_s_barrier();      // safe to overwrite buf[cur] next iter
  }

  // ---- fused epilogue: arg = C*(x2_i + x2_j) + log2e*dot, clamp <=0, exp2
  float cb[4];
#pragma unroll
  for (int n = 0; n < 4; ++n) cb[n] = lBx2[wc * 64 + n * 16 + (l & 15)];
  float local = 0.f;
#pragma unroll
  for (int m = 0; m < 8; ++m) {
#pragma unroll
    for (int j = 0; j < 4; ++j) {
      const float rc = lAx2[wr * 128 + m * 16 + ((l >> 4) * 4 + j)];
#pragma unroll
      for (int n = 0; n < 4; ++n) {
        float arg = fmaf(LOG2E, acc[m][n][j], rc + cb[n]);
        arg = fminf(arg, 0.f);
        local += exp2f(arg);
      }
    }
  }
#pragma unroll
  for (int off = 32; off > 0; off >>= 1) local += __shfl_xor(local, off);
  if (l == 0) wsum[w] = local;
  __syncthreads();
  if (tid == 0) {
    float tot = 0.f;
#pragma unroll
    for (int i = 0; i < 8; ++i) tot += wsum[i];
    atomicAdd(&accums[0], tot * wgt);
  }
}

__global__ void finalize_kernel(const float* __restrict__ accums, float* __restrict__ out) {
  out[0] = accums[0] * (1.f / ((float)NROWS * (float)NROWS));
}

extern "C" void kernel_launch(void* const* d_in, const int* in_sizes, int n_in,
                              void* d_out, int out_size, void* d_ws, size_t ws_size,
                              hipStream_t stream) {
  const float* S = (const float*)d_in[0];
  const float* T = (const float*)d_in[1];
  float* out = (float*)d_out;

  ushort* Sb = (ushort*)d_ws;                      // 4 MB
  ushort* Tb = Sb + (size_t)NROWS * DIM;           // 4 MB
  float* x2s = (float*)(Tb + (size_t)NROWS * DIM); // 32 KB
  float* x2t = x2s + NROWS;                        // 32 KB
  float* accums = x2t + NROWS;                     // [0]=sum

  prep_kernel<<<(2 * NROWS) / 4, 256, 0, stream>>>(S, T, Sb, Tb, x2s, x2t, accums);
  mmd_gemm<<<NBLK, 512, 0, stream>>>(Sb, Tb, x2s, x2t, accums);
  finalize_kernel<<<1, 1, 0, stream>>>(accums, out);
}

// Round 6
// 181.441 us; speedup vs baseline: 1.7223x; 1.0152x over previous
//
#include <hip/hip_runtime.h>
#include <hip/hip_bf16.h>

#define NROWS 8192
#define DIM 256
#define NT 32                     // 256-row tiles per matrix dim
#define TRI ((NT * (NT + 1)) / 2) // 528 triangular tiles
#define NBLK (2 * TRI + NT * NT)  // 2080 total blocks

typedef __attribute__((ext_vector_type(8))) short short8;
typedef __attribute__((ext_vector_type(4))) float f32x4;

__device__ __forceinline__ ushort f2bf(float f) {
  unsigned u = __float_as_uint(f);
  u += 0x7fffu + ((u >> 16) & 1u);   // round-to-nearest-even
  return (ushort)(u >> 16);
}
__device__ __forceinline__ float bf2f(ushort b) {
  return __uint_as_float(((unsigned)b) << 16);
}

// exp(-0.5*d2) = exp2(C*d2), C = -0.5*log2(e); C folded into x2 at prep
#define NEGHALF_LOG2E (-0.72134752044448170368f)
#define LOG2E          (1.44269504088896340736f)

// ---- prep: f32 -> bf16 + row sum-of-squares of the bf16-rounded values.
__global__ __launch_bounds__(256) void prep_kernel(
    const float* __restrict__ S, const float* __restrict__ T,
    ushort* __restrict__ Sb, ushort* __restrict__ Tb,
    float* __restrict__ x2s, float* __restrict__ x2t,
    float* __restrict__ accums) {
  if (blockIdx.x == 0 && threadIdx.x == 0) accums[0] = 0.f;
  const int w = threadIdx.x >> 6, l = threadIdx.x & 63;
  const int r = blockIdx.x * 4 + w;
  const float* src;
  ushort* dst;
  float* sq;
  int row;
  if (r < NROWS) { src = S; dst = Sb; sq = x2s; row = r; }
  else           { src = T; dst = Tb; sq = x2t; row = r - NROWS; }

  const float4 v = *(const float4*)(src + (size_t)row * DIM + l * 4);
  float vf[4] = {v.x, v.y, v.z, v.w};
  ushort b[4];
  float s = 0.f;
#pragma unroll
  for (int i = 0; i < 4; ++i) {
    b[i] = f2bf(vf[i]);
    float f = bf2f(b[i]);
    s += f * f;
  }
  *(ushort4*)(dst + (size_t)row * DIM + l * 4) = make_ushort4(b[0], b[1], b[2], b[3]);
#pragma unroll
  for (int off = 32; off > 0; off >>= 1) s += __shfl_xor(s, off);
  if (l == 0) sq[row] = s * NEGHALF_LOG2E;
}

__device__ __forceinline__ void gload_lds16(const void* g, void* lds) {
  __builtin_amdgcn_global_load_lds(
      (const __attribute__((address_space(1))) unsigned int*)g,
      (__attribute__((address_space(3))) unsigned int*)lds, 16, 0, 0);
}

// ---- fused GEMM + exp2 + reduce. 256x256 tile, 8 waves, BK=32,
// triple-buffered LDS, 2-ahead staging, counted vmcnt, phased MFMA.
__global__ __launch_bounds__(512, 2) void mmd_gemm(
    const ushort* __restrict__ Sb, const ushort* __restrict__ Tb,
    const float* __restrict__ x2s, const float* __restrict__ x2t,
    float* __restrict__ accums) {
  // [buf][row*32 + k]; physical 16B-slot sp holds global slot sp^((row>>1)&3)
  __shared__ __align__(16) ushort lA[3][256 * 32];
  __shared__ __align__(16) ushort lB[3][256 * 32];
  __shared__ float lAx2[256];
  __shared__ float lBx2[256];
  __shared__ float wsum[8];

  const int tid = threadIdx.x;
  const int l = tid & 63;
  const int w = tid >> 6;
  const int wr = w >> 2, wc = w & 3;   // 2(M) x 4(N) waves; wave tile 128x64

  // ---- tile decode: [0,TRI) SS lower-tri, [TRI,2TRI) TT lower-tri, rest ST
  const int bid = blockIdx.x;
  const ushort* Ap;
  const ushort* Bp;
  const float* a2;
  const float* b2;
  int tr, tc;
  float wgt;
  if (bid < 2 * TRI) {
    const int i = (bid < TRI) ? bid : bid - TRI;
    int g = (int)((sqrtf((float)(8 * i + 1)) - 1.0f) * 0.5f);
    g = min(max(g - 2, 0), NT - 1);
    tr = g;
    while (tr < NT - 1 && (tr + 1) * (tr + 2) / 2 <= i) ++tr;
    tc = i - tr * (tr + 1) / 2;        // tr >= tc
    wgt = (tr == tc) ? 1.f : 2.f;
    if (bid < TRI) { Ap = Sb; Bp = Sb; a2 = x2s; b2 = x2s; }
    else           { Ap = Tb; Bp = Tb; a2 = x2t; b2 = x2t; }
  } else {
    const int t = bid - 2 * TRI;
    tr = t >> 5; tc = t & 31;
    wgt = -2.f;
    Ap = Sb; Bp = Tb; a2 = x2s; b2 = x2t;
  }

  const ushort* gA = Ap + (size_t)(tr * 256) * DIM;
  const ushort* gB = Bp + (size_t)(tc * 256) * DIM;

  // stage half j (512 chunks) of K-tile kt into buf: dest lane-linear,
  // source slot pre-permuted so swizzled reads see logical k-order
#define STAGE2(kt, jj)                                                     \
  {                                                                        \
    const int c_ = (jj) * 512 + tid;                                       \
    const int row_ = c_ >> 2, sp_ = c_ & 3;                                \
    const int sl_ = sp_ ^ ((row_ >> 1) & 3);                               \
    const int buf_ = (kt) % 3;                                             \
    const size_t go_ = (size_t)row_ * DIM + (kt) * 32 + sl_ * 8;           \
    gload_lds16(gA + go_, &lA[buf_][c_ * 8]);                              \
    gload_lds16(gB + go_, &lB[buf_][c_ * 8]);                              \
  }

  // prologue: tiles 0 and 1 in flight (8 loads/thread, FIFO order)
  STAGE2(0, 0); STAGE2(0, 1);
  STAGE2(1, 0); STAGE2(1, 1);

  // x2 rows into LDS while loads fly
  if (tid < 256) lAx2[tid] = a2[tr * 256 + tid];
  else           lBx2[tid - 256] = b2[tc * 256 + tid - 256];

  f32x4 acc[8][4];
  const f32x4 zero = {0.f, 0.f, 0.f, 0.f};
#pragma unroll
  for (int m = 0; m < 8; ++m)
#pragma unroll
    for (int n = 0; n < 4; ++n) acc[m][n] = zero;

#pragma unroll
  for (int kt = 0; kt < 8; ++kt) {
    const int cur = kt % 3;
    if (kt == 7) { asm volatile("s_waitcnt vmcnt(0)" ::: "memory"); }
    else         { asm volatile("s_waitcnt vmcnt(4)" ::: "memory"); }  // tile kt landed, kt+1 in flight
    __builtin_amdgcn_s_barrier();
    asm volatile("" ::: "memory");

    // ---- phase 1: m-half 0 (16 MFMA); issue first half of tile kt+2
    if (kt < 6) STAGE2(kt + 2, 0);
    short8 bfv[4], af[4];
#pragma unroll
    for (int n = 0; n < 4; ++n) {
      const int row = wc * 64 + n * 16 + (l & 15);
      const int sp = (l >> 4) ^ ((row >> 1) & 3);
      bfv[n] = *(const short8*)&lB[cur][row * 32 + sp * 8];
    }
#pragma unroll
    for (int m = 0; m < 4; ++m) {
      const int row = wr * 128 + m * 16 + (l & 15);
      const int sp = (l >> 4) ^ ((row >> 1) & 3);
      af[m] = *(const short8*)&lA[cur][row * 32 + sp * 8];
    }
    __builtin_amdgcn_s_setprio(1);
#pragma unroll
    for (int m = 0; m < 4; ++m)
#pragma unroll
      for (int n = 0; n < 4; ++n)
        acc[m][n] = __builtin_amdgcn_mfma_f32_16x16x32_bf16(af[m], bfv[n], acc[m][n], 0, 0, 0);
    __builtin_amdgcn_s_setprio(0);
    __builtin_amdgcn_s_barrier();
    asm volatile("" ::: "memory");

    // ---- phase 2: m-half 1 (16 MFMA, bfv reused); second half of tile kt+2
    if (kt < 6) STAGE2(kt + 2, 1);
#pragma unroll
    for (int m = 0; m < 4; ++m) {
      const int row = wr * 128 + 64 + m * 16 + (l & 15);
      const int sp = (l >> 4) ^ ((row >> 1) & 3);
      af[m] = *(const short8*)&lA[cur][row * 32 + sp * 8];
    }
    __builtin_amdgcn_s_setprio(1);
#pragma unroll
    for (int m = 0; m < 4; ++m)
#pragma unroll
      for (int n = 0; n < 4; ++n)
        acc[4 + m][n] = __builtin_amdgcn_mfma_f32_16x16x32_bf16(af[m], bfv[n], acc[4 + m][n], 0, 0, 0);
    __builtin_amdgcn_s_setprio(0);
  }

  // ---- fused epilogue: arg = C*(x2_i + x2_j) + log2e*dot, clamp <=0, exp2
  float cb[4];
#pragma unroll
  for (int n = 0; n < 4; ++n) cb[n] = lBx2[wc * 64 + n * 16 + (l & 15)];
  float local = 0.f;
#pragma unroll
  for (int m = 0; m < 8; ++m) {
#pragma unroll
    for (int j = 0; j < 4; ++j) {
      const float rc = lAx2[wr * 128 + m * 16 + ((l >> 4) * 4 + j)];
#pragma unroll
      for (int n = 0; n < 4; ++n) {
        float arg = fmaf(LOG2E, acc[m][n][j], rc + cb[n]);
        arg = fminf(arg, 0.f);
        local += exp2f(arg);
      }
    }
  }
#pragma unroll
  for (int off = 32; off > 0; off >>= 1) local += __shfl_xor(local, off);
  if (l == 0) wsum[w] = local;
  __syncthreads();
  if (tid == 0) {
    float tot = 0.f;
#pragma unroll
    for (int i = 0; i < 8; ++i) tot += wsum[i];
    atomicAdd(&accums[0], tot * wgt);
  }
}

__global__ void finalize_kernel(const float* __restrict__ accums, float* __restrict__ out) {
  out[0] = accums[0] * (1.f / ((float)NROWS * (float)NROWS));
}

extern "C" void kernel_launch(void* const* d_in, const int* in_sizes, int n_in,
                              void* d_out, int out_size, void* d_ws, size_t ws_size,
                              hipStream_t stream) {
  const float* S = (const float*)d_in[0];
  const float* T = (const float*)d_in[1];
  float* out = (float*)d_out;

  ushort* Sb = (ushort*)d_ws;                      // 4 MB
  ushort* Tb = Sb + (size_t)NROWS * DIM;           // 4 MB
  float* x2s = (float*)(Tb + (size_t)NROWS * DIM); // 32 KB
  float* x2t = x2s + NROWS;                        // 32 KB
  float* accums = x2t + NROWS;                     // [0]=sum

  prep_kernel<<<(2 * NROWS) / 4, 256, 0, stream>>>(S, T, Sb, Tb, x2s, x2t, accums);
  mmd_gemm<<<NBLK, 512, 0, stream>>>(Sb, Tb, x2s, x2t, accums);
  finalize_kernel<<<1, 1, 0, stream>>>(accums, out);
}